// Round 3
// baseline (13281.947 us; speedup 1.0000x reference)
//
#include <hip/hip_runtime.h>
#include <hip/hip_bf16.h>
#include <math.h>

typedef __hip_bfloat16 bf16;

#define NN 50000
#define EE 150000
#define GR 32
#define LPG 8

static __device__ __forceinline__ float b2f(bf16 x){ return __bfloat162float(x); }
static __device__ __forceinline__ bf16 f2b(float x){ return __float2bfloat16(x); }
static __device__ __forceinline__ float ldf(bf16 x){ return __bfloat162float(x); }
static __device__ __forceinline__ float ldf(float x){ return x; }

// ---------------- utility ----------------
__global__ void k_zero(int* __restrict__ p, int n){
  int i = blockIdx.x*blockDim.x + threadIdx.x;
  if(i<n) p[i]=0;
}

// ---------------- CSR build ----------------
__global__ void k_hist(const int* __restrict__ dst, int* __restrict__ deg){
  int i = blockIdx.x*blockDim.x + threadIdx.x;
  if(i<EE) atomicAdd(&deg[dst[i]], 1);
}

__global__ void k_scan(const int* __restrict__ deg, int* __restrict__ rowptr){
  __shared__ int part[1024];
  int tid = threadIdx.x;
  const int n = NN;
  int chunk = (n + 1023)/1024;
  int start = tid*chunk;
  int end = start + chunk; if(end > n) end = n;
  int s = 0;
  for(int i=start;i<end;i++) s += deg[i];
  part[tid] = s; __syncthreads();
  for(int off=1; off<1024; off<<=1){
    int v = (tid>=off)? part[tid-off] : 0;
    __syncthreads();
    part[tid] += v;
    __syncthreads();
  }
  int run = (tid==0)? 0 : part[tid-1];
  for(int i=start;i<end;i++){ rowptr[i]=run; run += deg[i]; }
  if(tid==0) rowptr[n] = part[1023];
}

__global__ void k_scatter(const int* __restrict__ dst, const int* __restrict__ rowptr,
                          int* __restrict__ cursor, int* __restrict__ elist){
  int e = blockIdx.x*blockDim.x + threadIdx.x;
  if(e<EE){ int d=dst[e]; int p=atomicAdd(&cursor[d],1); elist[rowptr[d]+p]=e; }
}

// ------- time encoding: fp32 arg (mul then add, no FMA) to match f32 reference -------
__global__ void k_relenc(const int* __restrict__ src, const int* __restrict__ tt,
                         const int* __restrict__ lu, const float* __restrict__ tw,
                         const float* __restrict__ tb, bf16* __restrict__ rel){
  int i = blockIdx.x*blockDim.x + threadIdx.x;
  if(i >= EE*100) return;
  int e = i/100, c = i - e*100;
  float rt  = (float)(lu[src[e]] - tt[e]);          // |rt| < 2^24: exact
  float arg = __fadd_rn(__fmul_rn(rt, tw[c]), tb[c]); // matches np/jax f32 rounding
  rel[i] = f2b(cosf(arg));
}

// ---------------- strided GEMM: C = act(A@W + bias + addend), fp32 acc ----
// A [M,K] dtype TA (row stride lda), W [K,Nc] fp32 (row stride ldw), bias fp32 or null,
// addend fp32 (row stride ldadd) or null, C bf16 (row stride ldc). K % 100 == 0.
template<typename TA>
__global__ void k_gemm(const TA* __restrict__ A, int lda,
                       const float* __restrict__ W, int ldw,
                       const float* __restrict__ bias,
                       const float* __restrict__ addend, int ldadd,
                       bf16* __restrict__ C, int ldc,
                       int M, int K, int Nc, int act){
  __shared__ float As[GR*100];
  int row0 = blockIdx.y*GR;
  int col  = blockIdx.x*blockDim.x + threadIdx.x;
  float acc[GR];
#pragma unroll
  for(int r=0;r<GR;r++) acc[r]=0.f;
  for(int kc=0; kc<K; kc+=100){
    for(int idx=threadIdx.x; idx<GR*100; idx+=blockDim.x){
      int r = idx/100, k = idx - r*100;
      int row = row0 + r;
      As[idx] = (row<M)? ldf(A[(size_t)row*lda + kc + k]) : 0.f;
    }
    __syncthreads();
    if(col<Nc){
      const float* wp = W + (size_t)kc*ldw + col;
#pragma unroll 4
      for(int k=0;k<100;k++){
        float w = wp[(size_t)k*ldw];
#pragma unroll
        for(int r=0;r<GR;r++) acc[r] += As[r*100+k]*w;
      }
    }
    __syncthreads();
  }
  if(col<Nc){
    float bv = bias? bias[col] : 0.f;
    for(int r=0;r<GR;r++){
      int row = row0 + r;
      if(row>=M) break;
      float v = acc[r] + bv;
      if(addend) v += addend[(size_t)row*ldadd+col];
      if(act) v = fmaxf(v, 0.f);
      C[(size_t)row*ldc+col] = f2b(v);
    }
  }
}

// ---------------- edge-attr GEMM: A row = [rel(100,bf16) | msg(100,fp32)], K=200 ------
__global__ void k_gemm_edge(const bf16* __restrict__ rel, const float* __restrict__ msg,
                            const float* __restrict__ W, int ldw,
                            bf16* __restrict__ C, int M, int Nc){
  __shared__ float As[GR*200];
  int row0 = blockIdx.y*GR;
  int col  = blockIdx.x*blockDim.x + threadIdx.x;
  float acc[GR];
#pragma unroll
  for(int r=0;r<GR;r++) acc[r]=0.f;
  for(int idx=threadIdx.x; idx<GR*200; idx+=blockDim.x){
    int r = idx/200, k = idx - r*200;
    int row = row0 + r;
    float v = 0.f;
    if(row<M) v = (k<100)? b2f(rel[(size_t)row*100+k]) : msg[(size_t)row*100+(k-100)];
    As[idx] = v;
  }
  __syncthreads();
  if(col<Nc){
#pragma unroll 2
    for(int k=0;k<200;k++){
      float w = W[(size_t)k*ldw+col];
#pragma unroll
      for(int r=0;r<GR;r++) acc[r] += As[r*200+k]*w;
    }
    for(int r=0;r<GR;r++){
      int row = row0 + r;
      if(row>=M) break;
      C[(size_t)row*Nc+col] = f2b(acc[r]);
    }
  }
}

// ---------------- attention score (one head): alpha = 0.1 * q[dst]·(k[src]+e) ------
__global__ void k_alpha(const bf16* __restrict__ q, const bf16* __restrict__ k,
                        const bf16* __restrict__ eh, const int* __restrict__ src,
                        const int* __restrict__ dst, float* __restrict__ alpha){
  int e = blockIdx.x*blockDim.x + threadIdx.x;
  if(e >= EE) return;
  const bf16* qp = q + (size_t)dst[e]*100;
  const bf16* kp = k + (size_t)src[e]*100;
  const bf16* ep = eh + (size_t)e*100;
  float s = 0.f;
  for(int c=0;c<100;c++) s += b2f(qp[c])*(b2f(kp[c]) + b2f(ep[c]));
  alpha[e] = s * 0.1f;
}

// ---------------- per-node segment softmax (in place on alpha[E]) ----------------
__global__ void k_softmax(const int* __restrict__ rowptr, const int* __restrict__ elist,
                          float* __restrict__ alpha){
  int node = blockIdx.x*blockDim.x + threadIdx.x;
  if(node >= NN) return;
  int s0 = rowptr[node], s1 = rowptr[node+1];
  if(s0==s1) return;
  float m = -3.4e38f;
  for(int j=s0;j<s1;j++){ float a = alpha[elist[j]]; m = fmaxf(m,a); }
  float den = 0.f;
  for(int j=s0;j<s1;j++){
    int e = elist[j];
    float ex = expf(alpha[e]-m);
    alpha[e] = ex; den += ex;
  }
  float inv = 1.f/(den + 1e-16f);
  for(int j=s0;j<s1;j++) alpha[elist[j]] *= inv;
}

// ---------------- weighted aggregation (one head): agg[n] = Σ a*(v[src]+e) --------
__global__ void k_agg(const int* __restrict__ rowptr, const int* __restrict__ elist,
                      const int* __restrict__ src, const float* __restrict__ alpha,
                      const bf16* __restrict__ v, const bf16* __restrict__ eh,
                      float* __restrict__ agg){
  int i = blockIdx.x*blockDim.x + threadIdx.x;
  if(i >= NN*100) return;
  int node = i/100, c = i - node*100;
  int s0 = rowptr[node], s1 = rowptr[node+1];
  float s = 0.f;
  for(int j=s0;j<s1;j++){
    int e = elist[j];
    s += alpha[e]*(b2f(v[(size_t)src[e]*100+c]) + b2f(eh[(size_t)e*100+c]));
  }
  agg[i] = s;
}

// ---------------- fused link predictor: per-edge 4-layer MLP, LPG edges per block ----
__global__ __launch_bounds__(256) void k_linkpred(
    const bf16* __restrict__ h2, const int* __restrict__ srcv, const int* __restrict__ dstv,
    const float* __restrict__ wsrc, const float* __restrict__ bsrc,
    const float* __restrict__ wdst, const float* __restrict__ bdst,
    const float* __restrict__ w1, const float* __restrict__ pb1,
    const float* __restrict__ w2, const float* __restrict__ pb2,
    const float* __restrict__ w3, const float* __restrict__ pb3,
    const float* __restrict__ w4, const float* __restrict__ pb4,
    float* __restrict__ out)
{
  __shared__ float xs[LPG*100];
  __shared__ float xd[LPG*100];
  __shared__ float bufA[LPG*400];   // hh, then t2 (stride 200)
  __shared__ float bufB[LPG*800];   // t1, then t3 (stride 50)
  int tid = threadIdx.x;
  int e0 = blockIdx.x*LPG;
  for(int idx=tid; idx<LPG*100; idx+=256){
    int g = idx/100, c = idx - g*100;
    int e = e0 + g;
    float vs=0.f, vd=0.f;
    if(e<EE){ vs = b2f(h2[(size_t)srcv[e]*100+c]); vd = b2f(h2[(size_t)dstv[e]*100+c]); }
    xs[idx]=vs; xd[idx]=vd;
  }
  __syncthreads();
  if(tid<200){
    float accS[LPG], accD[LPG];
#pragma unroll
    for(int g=0;g<LPG;g++){ accS[g]=0.f; accD[g]=0.f; }
    for(int k=0;k<100;k++){
      float ws_ = wsrc[k*200+tid];
      float wd_ = wdst[k*200+tid];
#pragma unroll
      for(int g=0;g<LPG;g++){ accS[g]+=ws_*xs[g*100+k]; accD[g]+=wd_*xd[g*100+k]; }
    }
    float bs_=bsrc[tid], bd_=bdst[tid];
#pragma unroll
    for(int g=0;g<LPG;g++){ bufA[g*400+tid]=accS[g]+bs_; bufA[g*400+200+tid]=accD[g]+bd_; }
  }
  __syncthreads();
  for(int j=tid; j<800; j+=256){
    float acc[LPG];
#pragma unroll
    for(int g=0;g<LPG;g++) acc[g]=0.f;
    for(int k=0;k<400;k++){
      float w = w1[k*800+j];
#pragma unroll
      for(int g=0;g<LPG;g++) acc[g]+=w*bufA[g*400+k];
    }
    float bb = pb1[j];
#pragma unroll
    for(int g=0;g<LPG;g++) bufB[g*800+j]=tanhf(acc[g]+bb);
  }
  __syncthreads();
  if(tid<200){
    float acc[LPG];
#pragma unroll
    for(int g=0;g<LPG;g++) acc[g]=0.f;
    for(int k=0;k<800;k++){
      float w = w2[k*200+tid];
#pragma unroll
      for(int g=0;g<LPG;g++) acc[g]+=w*bufB[g*800+k];
    }
    float bb = pb2[tid];
#pragma unroll
    for(int g=0;g<LPG;g++) bufA[g*200+tid]=tanhf(acc[g]+bb);
  }
  __syncthreads();
  if(tid<50){
    float acc[LPG];
#pragma unroll
    for(int g=0;g<LPG;g++) acc[g]=0.f;
    for(int k=0;k<200;k++){
      float w = w3[k*50+tid];
#pragma unroll
      for(int g=0;g<LPG;g++) acc[g]+=w*bufA[g*200+k];
    }
    float bb = pb3[tid];
#pragma unroll
    for(int g=0;g<LPG;g++) bufB[g*50+tid]=tanhf(acc[g]+bb);
  }
  __syncthreads();
  if(tid < LPG*2){
    int g = tid>>1, j = tid&1;
    int e = e0 + g;
    if(e<EE){
      float acc = 0.f;
      for(int k=0;k<50;k++) acc += w4[k*2+j]*bufB[g*50+k];
      out[(size_t)e*2+j] = acc + pb4[j];
    }
  }
}

extern "C" void kernel_launch(void* const* d_in, const int* in_sizes, int n_in,
                              void* d_out, int out_size, void* d_ws, size_t ws_size,
                              hipStream_t stream){
  const float* x       = (const float*)d_in[0];
  const float* msg     = (const float*)d_in[1];
  const float* time_w  = (const float*)d_in[2];
  const float* time_b  = (const float*)d_in[3];
  const float* c1_qw=(const float*)d_in[4];  const float* c1_qb=(const float*)d_in[5];
  const float* c1_kw=(const float*)d_in[6];  const float* c1_kb=(const float*)d_in[7];
  const float* c1_vw=(const float*)d_in[8];  const float* c1_vb=(const float*)d_in[9];
  const float* c1_ew=(const float*)d_in[10];
  const float* c1_sw=(const float*)d_in[11]; const float* c1_sb=(const float*)d_in[12];
  const float* c2_qw=(const float*)d_in[13]; const float* c2_qb=(const float*)d_in[14];
  const float* c2_kw=(const float*)d_in[15]; const float* c2_kb=(const float*)d_in[16];
  const float* c2_vw=(const float*)d_in[17]; const float* c2_vb=(const float*)d_in[18];
  const float* c2_ew=(const float*)d_in[19];
  const float* c2_sw=(const float*)d_in[20]; const float* c2_sb=(const float*)d_in[21];
  const float* lp_src_w=(const float*)d_in[22]; const float* lp_src_b=(const float*)d_in[23];
  const float* lp_dst_w=(const float*)d_in[24]; const float* lp_dst_b=(const float*)d_in[25];
  const float* lp1_w=(const float*)d_in[26]; const float* lp1_b=(const float*)d_in[27];
  const float* lp2_w=(const float*)d_in[28]; const float* lp2_b=(const float*)d_in[29];
  const float* lp3_w=(const float*)d_in[30]; const float* lp3_b=(const float*)d_in[31];
  const float* lp4_w=(const float*)d_in[32]; const float* lp4_b=(const float*)d_in[33];
  const int* last_update=(const int*)d_in[34];
  const int* tt =(const int*)d_in[35];
  const int* edge_index=(const int*)d_in[36];
  const int* src = edge_index;
  const int* dst = edge_index + EE;
  float* out = (float*)d_out;

  // ---- workspace layout: identical byte footprint to round 2 (proved in-bounds) ----
  char* ws = (char*)d_ws;
  bf16*  h1    = (bf16*) (ws + 0);           // N*800 bf16  [0,80M)
  bf16*  rel   = (bf16*) (ws + 80000000);    // E*100 bf16  [80M,110M)
  bf16*  eh    = (bf16*) (ws + 110000000);   // E*100 bf16  (per-head e / e2)
  bf16*  qh    = (bf16*) (ws + 140000000);   // N*100 bf16
  bf16*  kh    = (bf16*) (ws + 150000000);   // N*100 bf16
  bf16*  vh    = (bf16*) (ws + 160000000);   // N*100 bf16
  float* aggh  = (float*)(ws + 170000000);   // N*100 fp32
  float* alpha = (float*)(ws + 190000000);   // E fp32
  int*   rowptr= (int*)  (ws + 190600000);   // N+1
  int*   elist = (int*)  (ws + 190800064);   // E
  int*   deg   = (int*)  (ws + 191400064);   // N
  int*   cursor= (int*)  (ws + 191600064);   // N
  bf16*  h2    = (bf16*) (ws + 191800064);   // N*100 bf16 -> ends 201,800,064

  // CSR build
  k_zero   <<<(NN+255)/256, 256, 0, stream>>>(deg, NN);
  k_zero   <<<(NN+255)/256, 256, 0, stream>>>(cursor, NN);
  k_hist   <<<(EE+255)/256, 256, 0, stream>>>(dst, deg);
  k_scan   <<<1, 1024, 0, stream>>>(deg, rowptr);
  k_scatter<<<(EE+255)/256, 256, 0, stream>>>(dst, rowptr, cursor, elist);

  // time encoding
  k_relenc<<<(EE*100+255)/256, 256, 0, stream>>>(src, tt, last_update, time_w, time_b, rel);

  dim3 gN (1, (NN+GR-1)/GR);
  dim3 gE (1, (EE+GR-1)/GR);

  // ---- conv1, one head at a time (column strips of the H1=800 weights) ----
  for(int h=0; h<8; h++){
    k_gemm<float><<<gN, 128, 0, stream>>>(x, 100, c1_qw + h*100, 800, c1_qb + h*100,
                                          nullptr, 0, qh, 100, NN, 100, 100, 0);
    k_gemm<float><<<gN, 128, 0, stream>>>(x, 100, c1_kw + h*100, 800, c1_kb + h*100,
                                          nullptr, 0, kh, 100, NN, 100, 100, 0);
    k_gemm<float><<<gN, 128, 0, stream>>>(x, 100, c1_vw + h*100, 800, c1_vb + h*100,
                                          nullptr, 0, vh, 100, NN, 100, 100, 0);
    k_gemm_edge<<<gE, 128, 0, stream>>>(rel, msg, c1_ew + h*100, 800, eh, EE, 100);
    k_alpha  <<<(EE+255)/256, 256, 0, stream>>>(qh, kh, eh, src, dst, alpha);
    k_softmax<<<(NN+255)/256, 256, 0, stream>>>(rowptr, elist, alpha);
    k_agg    <<<(NN*100+255)/256, 256, 0, stream>>>(rowptr, elist, src, alpha, vh, eh, aggh);
    k_gemm<float><<<gN, 128, 0, stream>>>(x, 100, c1_sw + h*100, 800, c1_sb + h*100,
                                          aggh, 100, h1 + h*100, 800, NN, 100, 100, 1);
  }

  // ---- conv2 (single head, reuses per-head buffers) ----
  k_gemm<bf16><<<gN, 128, 0, stream>>>(h1, 800, c2_qw, 100, c2_qb, nullptr, 0, qh, 100, NN, 800, 100, 0);
  k_gemm<bf16><<<gN, 128, 0, stream>>>(h1, 800, c2_kw, 100, c2_kb, nullptr, 0, kh, 100, NN, 800, 100, 0);
  k_gemm<bf16><<<gN, 128, 0, stream>>>(h1, 800, c2_vw, 100, c2_vb, nullptr, 0, vh, 100, NN, 800, 100, 0);
  k_gemm_edge<<<gE, 128, 0, stream>>>(rel, msg, c2_ew, 100, eh, EE, 100);
  k_alpha  <<<(EE+255)/256, 256, 0, stream>>>(qh, kh, eh, src, dst, alpha);
  k_softmax<<<(NN+255)/256, 256, 0, stream>>>(rowptr, elist, alpha);
  k_agg    <<<(NN*100+255)/256, 256, 0, stream>>>(rowptr, elist, src, alpha, vh, eh, aggh);
  k_gemm<bf16><<<gN, 128, 0, stream>>>(h1, 800, c2_sw, 100, c2_sb, aggh, 100, h2, 100, NN, 800, 100, 1);

  // ---- fused link predictor ----
  k_linkpred<<<(EE+LPG-1)/LPG, 256, 0, stream>>>(h2, src, dst,
      lp_src_w, lp_src_b, lp_dst_w, lp_dst_b,
      lp1_w, lp1_b, lp2_w, lp2_b, lp3_w, lp3_b, lp4_w, lp4_b, out);

  (void)in_sizes; (void)n_in; (void)out_size; (void)ws_size;
}

// Round 4
// 6146.435 us; speedup vs baseline: 2.1609x; 2.1609x over previous
//
#include <hip/hip_runtime.h>
#include <hip/hip_bf16.h>
#include <math.h>

typedef __hip_bfloat16 bf16;
typedef short s16x8 __attribute__((ext_vector_type(8)));
typedef float f32x4 __attribute__((ext_vector_type(4)));

#define NN 50000
#define EE 150000

static __device__ __forceinline__ float b2f(bf16 x){ return __bfloat162float(x); }
static __device__ __forceinline__ bf16 f2b(float x){ return __float2bfloat16(x); }

// ---------------- utility ----------------
__global__ void k_zero(int* __restrict__ p, int n){
  int i = blockIdx.x*blockDim.x + threadIdx.x;
  if(i<n) p[i]=0;
}

// ---------------- CSR build ----------------
__global__ void k_hist(const int* __restrict__ dst, int* __restrict__ deg){
  int i = blockIdx.x*blockDim.x + threadIdx.x;
  if(i<EE) atomicAdd(&deg[dst[i]], 1);
}

__global__ void k_scan(const int* __restrict__ deg, int* __restrict__ rowptr){
  __shared__ int part[1024];
  int tid = threadIdx.x;
  const int n = NN;
  int chunk = (n + 1023)/1024;
  int start = tid*chunk;
  int end = start + chunk; if(end > n) end = n;
  int s = 0;
  for(int i=start;i<end;i++) s += deg[i];
  part[tid] = s; __syncthreads();
  for(int off=1; off<1024; off<<=1){
    int v = (tid>=off)? part[tid-off] : 0;
    __syncthreads();
    part[tid] += v;
    __syncthreads();
  }
  int run = (tid==0)? 0 : part[tid-1];
  for(int i=start;i<end;i++){ rowptr[i]=run; run += deg[i]; }
  if(tid==0) rowptr[n] = part[1023];
}

__global__ void k_scatter(const int* __restrict__ dst, const int* __restrict__ rowptr,
                          int* __restrict__ cursor, int* __restrict__ elist){
  int e = blockIdx.x*blockDim.x + threadIdx.x;
  if(e<EE){ int d=dst[e]; int p=atomicAdd(&cursor[d],1); elist[rowptr[d]+p]=e; }
}

// ------- time encoding: fp32 arg (mul then add, no FMA) to match f32 reference -------
__global__ void k_relenc(const int* __restrict__ src, const int* __restrict__ tt,
                         const int* __restrict__ lu, const float* __restrict__ tw,
                         const float* __restrict__ tb, bf16* __restrict__ rel){
  int i = blockIdx.x*blockDim.x + threadIdx.x;
  if(i >= EE*100) return;
  int e = i/100, c = i - e*100;
  float rt  = (float)(lu[src[e]] - tt[e]);
  float arg = __fadd_rn(__fmul_rn(rt, tw[c]), tb[c]);
  rel[i] = f2b(cosf(arg));
}

// ------- weight convert: W[K,N] fp32 -> WT[nrows][kpad] bf16 (transposed, zero-pad) ---
__global__ void k_wt(const float* __restrict__ W, int K, int N,
                     bf16* __restrict__ WT, int kpad, int nrows){
  int i = blockIdx.x*blockDim.x + threadIdx.x;
  if(i >= nrows*kpad) return;
  int n = i / kpad, k = i - n*kpad;
  float v = (n<N && k<K)? W[(size_t)k*N + n] : 0.f;
  WT[i] = f2b(v);
}

// ---------------- MFMA GEMM: C[M,100] = act(A@W + bias + addend) ----------------
// A row = A1(bf16) for k<ksplit else A2(fp32, col k-ksplit). WT: [n][kpad] bf16,
// zero-padded (n>=N or k>=K -> 0). N fixed 100 (7 col-tiles of 16, masked).
// MFMA layout (m89/m120-verified): A[m=lo][k=quad*8+j], B[k=quad*8+j][n=lo],
// C col=lo,row=quad*4+r.
#define AK 128
#define AST 136   // +8 bf16 pad: row stride 272B = 68 words -> 2-way bank alias (free)

__global__ __launch_bounds__(256) void mm_mfma(
    const bf16* __restrict__ A1, int lda1, int ksplit,
    const float* __restrict__ A2, int lda2,
    const bf16* __restrict__ WT, int kpad,
    const float* __restrict__ bias,
    const bf16* __restrict__ addend,   // [M,100] bf16 or null
    bf16* __restrict__ C, int ldc,
    int M, int K, int act)
{
  __shared__ __align__(16) bf16 As[64*AST];
  int tid = threadIdx.x;
  int wave = tid>>6, lane = tid&63;
  int quad = lane>>4, lo = lane&15;
  int m0 = blockIdx.x*64;
  f32x4 acc[7];
#pragma unroll
  for(int t=0;t<7;t++) acc[t]=(f32x4){0.f,0.f,0.f,0.f};
  int nchunks = kpad/AK;
  for(int kc=0; kc<nchunks; kc++){
    int kbase = kc*AK;
    for(int idx=tid; idx<64*AK; idx+=256){
      int r = idx>>7, k = idx & 127;
      int row = m0 + r;
      int kk = kbase + k;
      float v = 0.f;
      if(row < M && kk < K){
        v = (kk < ksplit)? b2f(A1[(size_t)row*lda1+kk]) : A2[(size_t)row*lda2 + (kk-ksplit)];
      }
      As[r*AST + k] = f2b(v);
    }
    __syncthreads();
    const bf16* arow = As + (wave*16 + lo)*AST;
#pragma unroll
    for(int ks=0; ks<4; ks++){
      s16x8 af = *(const s16x8*)(arow + ks*32 + quad*8);
#pragma unroll
      for(int nt=0; nt<7; nt++){
        const bf16* bp = WT + (size_t)(nt*16+lo)*kpad + kbase + ks*32 + quad*8;
        s16x8 bfr = *(const s16x8*)bp;
        acc[nt] = __builtin_amdgcn_mfma_f32_16x16x32_bf16(af, bfr, acc[nt], 0,0,0);
      }
    }
    __syncthreads();
  }
  int mrow0 = m0 + wave*16 + quad*4;
#pragma unroll
  for(int nt=0; nt<7; nt++){
    int col = nt*16 + lo;
    if(col >= 100) continue;
    float bv = bias? bias[col] : 0.f;
#pragma unroll
    for(int r=0;r<4;r++){
      int row = mrow0 + r;
      if(row >= M) continue;
      float v = acc[nt][r] + bv;
      if(addend) v += b2f(addend[(size_t)row*100+col]);
      if(act) v = fmaxf(v,0.f);
      C[(size_t)row*ldc+col] = f2b(v);
    }
  }
}

// ---------------- attention score (one head): alpha = 0.1 * q[dst]·(k[src]+e) ------
__global__ void k_alpha(const bf16* __restrict__ q, const bf16* __restrict__ k,
                        const bf16* __restrict__ eh, const int* __restrict__ src,
                        const int* __restrict__ dst, float* __restrict__ alpha){
  int e = blockIdx.x*blockDim.x + threadIdx.x;
  if(e >= EE) return;
  const bf16* qp = q + (size_t)dst[e]*100;
  const bf16* kp = k + (size_t)src[e]*100;
  const bf16* ep = eh + (size_t)e*100;
  float s = 0.f;
  for(int c=0;c<100;c++) s += b2f(qp[c])*(b2f(kp[c]) + b2f(ep[c]));
  alpha[e] = s * 0.1f;
}

// ---------------- per-node segment softmax (in place on alpha[E]) ----------------
__global__ void k_softmax(const int* __restrict__ rowptr, const int* __restrict__ elist,
                          float* __restrict__ alpha){
  int node = blockIdx.x*blockDim.x + threadIdx.x;
  if(node >= NN) return;
  int s0 = rowptr[node], s1 = rowptr[node+1];
  if(s0==s1) return;
  float m = -3.4e38f;
  for(int j=s0;j<s1;j++){ float a = alpha[elist[j]]; m = fmaxf(m,a); }
  float den = 0.f;
  for(int j=s0;j<s1;j++){
    int e = elist[j];
    float ex = expf(alpha[e]-m);
    alpha[e] = ex; den += ex;
  }
  float inv = 1.f/(den + 1e-16f);
  for(int j=s0;j<s1;j++) alpha[elist[j]] *= inv;
}

// ---------------- weighted aggregation (one head): agg[n] = Σ a*(v[src]+e), bf16 out --
__global__ void k_aggb(const int* __restrict__ rowptr, const int* __restrict__ elist,
                       const int* __restrict__ src, const float* __restrict__ alpha,
                       const bf16* __restrict__ v, const bf16* __restrict__ eh,
                       bf16* __restrict__ agg){
  int i = blockIdx.x*blockDim.x + threadIdx.x;
  if(i >= NN*100) return;
  int node = i/100, c = i - node*100;
  int s0 = rowptr[node], s1 = rowptr[node+1];
  float s = 0.f;
  for(int j=s0;j<s1;j++){
    int e = elist[j];
    s += alpha[e]*(b2f(v[(size_t)src[e]*100+c]) + b2f(eh[(size_t)e*100+c]));
  }
  agg[i] = f2b(s);
}

// ---------------- fused MFMA link predictor: 32 edges per block ----------------
// layer GEMM on a 32-row LDS tile: O[32,nvalid] = act(A[32,K] @ WT + bias)
__device__ __forceinline__ void lp_gemm(const bf16* Alds, int ast,
    const bf16* __restrict__ WT, int kpad, int ksteps,
    const float* __restrict__ bias, int ntiles, int nvalid,
    bf16* Olds, int ost, int act_tanh, int coloff,
    int wave, int quad, int lo)
{
  int total = 2*ntiles;
  for(int t=wave; t<total; t+=4){
    int mt = t & 1, nt = t >> 1;
    f32x4 acc = (f32x4){0.f,0.f,0.f,0.f};
    const bf16* ar = Alds + (mt*16+lo)*ast;
    const bf16* br = WT + (size_t)(nt*16+lo)*kpad;
    for(int ks=0; ks<ksteps; ks++){
      s16x8 af = *(const s16x8*)(ar + ks*32 + quad*8);
      s16x8 bfr = *(const s16x8*)(br + ks*32 + quad*8);
      acc = __builtin_amdgcn_mfma_f32_16x16x32_bf16(af, bfr, acc, 0,0,0);
    }
    int col = nt*16+lo;
    if(col < nvalid){
      float bv = bias ? bias[col] : 0.f;
#pragma unroll
      for(int r=0;r<4;r++){
        float v = acc[r] + bv;
        if(act_tanh) v = tanhf(v);
        Olds[(mt*16+quad*4+r)*ost + coloff + col] = f2b(v);
      }
    }
  }
}

__global__ __launch_bounds__(256) void k_linkpred(
    const bf16* __restrict__ h2, const int* __restrict__ srcv, const int* __restrict__ dstv,
    const bf16* __restrict__ wst, const float* __restrict__ bsrc,
    const bf16* __restrict__ wdt, const float* __restrict__ bdst,
    const bf16* __restrict__ w1t, const float* __restrict__ pb1,
    const bf16* __restrict__ w2t, const float* __restrict__ pb2,
    const bf16* __restrict__ w3t, const float* __restrict__ pb3,
    const float* __restrict__ w4, const float* __restrict__ pb4,
    float* __restrict__ out)
{
  // LDS row strides chosen: 16B-aligned, bank offset per row = 2-way alias only.
  __shared__ __align__(16) bf16 sm_xs[32*136];   // x[src] K=100 pad 128
  __shared__ __align__(16) bf16 sm_xd[32*136];   // x[dst]
  __shared__ __align__(16) bf16 sm_hh[32*424];   // hh K=400 pad 416; later t2 (stride 232)
  __shared__ __align__(16) bf16 sm_t1[32*808];   // t1 K=800
  int tid = threadIdx.x;
  int wave = tid>>6, lane = tid&63;
  int quad = lane>>4, lo = lane&15;
  int e0 = blockIdx.x*32;

  // gather h2 rows (zero-pad k=100..127, zero rows for e>=EE)
  for(int idx=tid; idx<32*128; idx+=256){
    int g = idx>>7, k = idx&127;
    int e = e0 + g;
    float vs=0.f, vd=0.f;
    if(e<EE && k<100){
      vs = b2f(h2[(size_t)srcv[e]*100+k]);
      vd = b2f(h2[(size_t)dstv[e]*100+k]);
    }
    sm_xs[g*136+k] = f2b(vs);
    sm_xd[g*136+k] = f2b(vd);
  }
  // zero hh frag-pad cols 400..423 (read by layer-2 k-step 12)
  for(int idx=tid; idx<32*24; idx+=256){
    int r = idx/24, c = idx-r*24;
    sm_hh[r*424+400+c] = f2b(0.f);
  }
  __syncthreads();

  // layer 1: hh[:,0:200] = h2[src]@wsrc+bsrc ; hh[:,200:400] = h2[dst]@wdst+bdst
  lp_gemm(sm_xs, 136, wst, 128, 4, bsrc, 13, 200, sm_hh, 424, 0, 0,   wave, quad, lo);
  lp_gemm(sm_xd, 136, wdt, 128, 4, bdst, 13, 200, sm_hh, 424, 0, 200, wave, quad, lo);
  __syncthreads();

  // layer 2: t1 = tanh(hh @ w1 + b1)  [K=400->13 ksteps, N=800]
  lp_gemm(sm_hh, 424, w1t, 512, 13, pb1, 50, 800, sm_t1, 808, 1, 0, wave, quad, lo);
  __syncthreads();

  // layer 3: t2 = tanh(t1 @ w2 + b2)  [K=800->25, N=200] -> overlay hh region, stride 232
  bf16* t2 = sm_hh;
  for(int idx=tid; idx<32*32; idx+=256){           // zero t2 pad cols 200..231
    int r = idx>>5, c = idx&31;
    t2[r*232+200+c] = f2b(0.f);
  }
  lp_gemm(sm_t1, 808, w2t, 896, 25, pb2, 13, 200, t2, 232, 1, 0, wave, quad, lo);
  __syncthreads();

  // layer 4: t3 = tanh(t2 @ w3 + b3)  [K=200->7, N=50] -> overlay xs region, stride 50
  bf16* t3 = sm_xs;
  lp_gemm(t2, 232, w3t, 256, 7, pb3, 4, 50, t3, 50, 1, 0, wave, quad, lo);
  __syncthreads();

  // final: out = t3 @ w4 + b4 (fp32 scalar)
  if(tid < 64){
    int g = tid>>1, j = tid&1;
    int e = e0 + g;
    if(e < EE){
      float s = 0.f;
      for(int k=0;k<50;k++) s += b2f(t3[g*50+k])*w4[k*2+j];
      out[(size_t)e*2+j] = s + pb4[j];
    }
  }
}

extern "C" void kernel_launch(void* const* d_in, const int* in_sizes, int n_in,
                              void* d_out, int out_size, void* d_ws, size_t ws_size,
                              hipStream_t stream){
  const float* x       = (const float*)d_in[0];
  const float* msg     = (const float*)d_in[1];
  const float* time_w  = (const float*)d_in[2];
  const float* time_b  = (const float*)d_in[3];
  const float* c1_qw=(const float*)d_in[4];  const float* c1_qb=(const float*)d_in[5];
  const float* c1_kw=(const float*)d_in[6];  const float* c1_kb=(const float*)d_in[7];
  const float* c1_vw=(const float*)d_in[8];  const float* c1_vb=(const float*)d_in[9];
  const float* c1_ew=(const float*)d_in[10];
  const float* c1_sw=(const float*)d_in[11]; const float* c1_sb=(const float*)d_in[12];
  const float* c2_qw=(const float*)d_in[13]; const float* c2_qb=(const float*)d_in[14];
  const float* c2_kw=(const float*)d_in[15]; const float* c2_kb=(const float*)d_in[16];
  const float* c2_vw=(const float*)d_in[17]; const float* c2_vb=(const float*)d_in[18];
  const float* c2_ew=(const float*)d_in[19];
  const float* c2_sw=(const float*)d_in[20]; const float* c2_sb=(const float*)d_in[21];
  const float* lp_src_w=(const float*)d_in[22]; const float* lp_src_b=(const float*)d_in[23];
  const float* lp_dst_w=(const float*)d_in[24]; const float* lp_dst_b=(const float*)d_in[25];
  const float* lp1_w=(const float*)d_in[26]; const float* lp1_b=(const float*)d_in[27];
  const float* lp2_w=(const float*)d_in[28]; const float* lp2_b=(const float*)d_in[29];
  const float* lp3_w=(const float*)d_in[30]; const float* lp3_b=(const float*)d_in[31];
  const float* lp4_w=(const float*)d_in[32]; const float* lp4_b=(const float*)d_in[33];
  const int* last_update=(const int*)d_in[34];
  const int* tt =(const int*)d_in[35];
  const int* edge_index=(const int*)d_in[36];
  const int* src = edge_index;
  const int* dst = edge_index + EE;
  float* out = (float*)d_out;

  // ---- workspace layout: peak 195.3 MB (< proved-safe 201.8 MB) ----
  char* ws = (char*)d_ws;
  bf16*  h1    = (bf16*) (ws + 0);             // N*800 bf16
  bf16*  rel   = (bf16*) (ws + 80000000);      // E*100 bf16
  bf16*  eh    = (bf16*) (ws + 110000000);     // E*100 bf16 (per-head)
  bf16*  qh    = (bf16*) (ws + 140000000);     // N*100 bf16
  bf16*  kh    = (bf16*) (ws + 150000000);
  bf16*  vh    = (bf16*) (ws + 160000000);
  bf16*  aggb  = (bf16*) (ws + 170000000);     // N*100 bf16
  bf16*  h2    = (bf16*) (ws + 180000000);     // N*100 bf16
  float* alpha = (float*)(ws + 190000000);     // E fp32
  int*   rowptr= (int*)  (ws + 190600064);     // N+1
  int*   elist = (int*)  (ws + 190800128);     // E
  int*   deg   = (int*)  (ws + 191400192);     // N
  int*   cursor= (int*)  (ws + 191600192);     // N
  // bf16 transposed/padded weights
  bf16* c1_qwt = (bf16*)(ws + 191800192);  // [816][128]
  bf16* c1_kwt = (bf16*)(ws + 192009088);
  bf16* c1_vwt = (bf16*)(ws + 192217984);
  bf16* c1_swt = (bf16*)(ws + 192426880);
  bf16* c1_ewt = (bf16*)(ws + 192635776);  // [816][256]
  bf16* c2_qwt = (bf16*)(ws + 193053568);  // [112][896]
  bf16* c2_kwt = (bf16*)(ws + 193254272);
  bf16* c2_vwt = (bf16*)(ws + 193454976);
  bf16* c2_swt = (bf16*)(ws + 193655680);
  bf16* c2_ewt = (bf16*)(ws + 193856384);  // [112][256]
  bf16* lpswt  = (bf16*)(ws + 193913728);  // [208][128]
  bf16* lpdwt  = (bf16*)(ws + 193966976);
  bf16* lp1t   = (bf16*)(ws + 194020224);  // [800][512]
  bf16* lp2t   = (bf16*)(ws + 194839424);  // [208][896]
  bf16* lp3t   = (bf16*)(ws + 195212160);  // [64][256] -> ends 195,244,928

  // ---- weight conversion (transpose + bf16 + zero-pad) ----
  #define WTL(W,K,N,WT,KP,NR) k_wt<<<((NR)*(KP)+255)/256,256,0,stream>>>(W,K,N,WT,KP,NR)
  WTL(c1_qw,100,800,c1_qwt,128,816);  WTL(c1_kw,100,800,c1_kwt,128,816);
  WTL(c1_vw,100,800,c1_vwt,128,816);  WTL(c1_sw,100,800,c1_swt,128,816);
  WTL(c1_ew,200,800,c1_ewt,256,816);
  WTL(c2_qw,800,100,c2_qwt,896,112);  WTL(c2_kw,800,100,c2_kwt,896,112);
  WTL(c2_vw,800,100,c2_vwt,896,112);  WTL(c2_sw,800,100,c2_swt,896,112);
  WTL(c2_ew,200,100,c2_ewt,256,112);
  WTL(lp_src_w,100,200,lpswt,128,208); WTL(lp_dst_w,100,200,lpdwt,128,208);
  WTL(lp1_w,400,800,lp1t,512,800);
  WTL(lp2_w,800,200,lp2t,896,208);
  WTL(lp3_w,200,50,lp3t,256,64);
  #undef WTL

  // ---- CSR build ----
  k_zero   <<<(NN+255)/256, 256, 0, stream>>>(deg, NN);
  k_zero   <<<(NN+255)/256, 256, 0, stream>>>(cursor, NN);
  k_hist   <<<(EE+255)/256, 256, 0, stream>>>(dst, deg);
  k_scan   <<<1, 1024, 0, stream>>>(deg, rowptr);
  k_scatter<<<(EE+255)/256, 256, 0, stream>>>(dst, rowptr, cursor, elist);

  // ---- time encoding ----
  k_relenc<<<(EE*100+255)/256, 256, 0, stream>>>(src, tt, last_update, time_w, time_b, rel);

  int gN = (NN+63)/64, gE = (EE+63)/64;

  // ---- conv1, one head at a time ----
  for(int h=0; h<8; h++){
    mm_mfma<<<gN,256,0,stream>>>(nullptr,0,0, x,100, c1_qwt + (size_t)h*100*128,128,
                                 c1_qb + h*100, nullptr, qh,100, NN,100,0);
    mm_mfma<<<gN,256,0,stream>>>(nullptr,0,0, x,100, c1_kwt + (size_t)h*100*128,128,
                                 c1_kb + h*100, nullptr, kh,100, NN,100,0);
    mm_mfma<<<gN,256,0,stream>>>(nullptr,0,0, x,100, c1_vwt + (size_t)h*100*128,128,
                                 c1_vb + h*100, nullptr, vh,100, NN,100,0);
    mm_mfma<<<gE,256,0,stream>>>(rel,100,100, msg,100, c1_ewt + (size_t)h*100*256,256,
                                 nullptr, nullptr, eh,100, EE,200,0);
    k_alpha  <<<(EE+255)/256, 256, 0, stream>>>(qh, kh, eh, src, dst, alpha);
    k_softmax<<<(NN+255)/256, 256, 0, stream>>>(rowptr, elist, alpha);
    k_aggb   <<<(NN*100+255)/256, 256, 0, stream>>>(rowptr, elist, src, alpha, vh, eh, aggb);
    mm_mfma<<<gN,256,0,stream>>>(nullptr,0,0, x,100, c1_swt + (size_t)h*100*128,128,
                                 c1_sb + h*100, aggb, h1 + h*100,800, NN,100,1);
  }

  // ---- conv2 (single head) ----
  mm_mfma<<<gN,256,0,stream>>>(h1,800,800, nullptr,0, c2_qwt,896, c2_qb, nullptr, qh,100, NN,800,0);
  mm_mfma<<<gN,256,0,stream>>>(h1,800,800, nullptr,0, c2_kwt,896, c2_kb, nullptr, kh,100, NN,800,0);
  mm_mfma<<<gN,256,0,stream>>>(h1,800,800, nullptr,0, c2_vwt,896, c2_vb, nullptr, vh,100, NN,800,0);
  mm_mfma<<<gE,256,0,stream>>>(rel,100,100, msg,100, c2_ewt,256, nullptr, nullptr, eh,100, EE,200,0);
  k_alpha  <<<(EE+255)/256, 256, 0, stream>>>(qh, kh, eh, src, dst, alpha);
  k_softmax<<<(NN+255)/256, 256, 0, stream>>>(rowptr, elist, alpha);
  k_aggb   <<<(NN*100+255)/256, 256, 0, stream>>>(rowptr, elist, src, alpha, vh, eh, aggb);
  mm_mfma<<<gN,256,0,stream>>>(h1,800,800, nullptr,0, c2_swt,896, c2_sb, aggb, h2,100, NN,800,1);

  // ---- fused MFMA link predictor ----
  k_linkpred<<<(EE+31)/32, 256, 0, stream>>>(h2, src, dst,
      lpswt, lp_src_b, lpdwt, lp_dst_b,
      lp1t, lp1_b, lp2t, lp2_b, lp3t, lp3_b, lp4_w, lp4_b, out);

  (void)in_sizes; (void)n_in; (void)out_size; (void)ws_size;
}

// Round 5
// 5333.981 us; speedup vs baseline: 2.4901x; 1.1523x over previous
//
#include <hip/hip_runtime.h>
#include <hip/hip_bf16.h>
#include <math.h>

typedef __hip_bfloat16 bf16;
typedef short s16x8 __attribute__((ext_vector_type(8)));
typedef float f32x4 __attribute__((ext_vector_type(4)));

#define NN 50000
#define EE 150000

static __device__ __forceinline__ float b2f(bf16 x){ return __bfloat162float(x); }
static __device__ __forceinline__ bf16 f2b(float x){ return __float2bfloat16(x); }
// bf16 pair packed in u32 (little-endian: lo16 = even element)
static __device__ __forceinline__ float u2f_lo(unsigned u){ union{unsigned i;float f;}c; c.i=u<<16; return c.f; }
static __device__ __forceinline__ float u2f_hi(unsigned u){ union{unsigned i;float f;}c; c.i=u&0xffff0000u; return c.f; }

// ---------------- utility ----------------
__global__ void k_zero(int* __restrict__ p, int n){
  int i = blockIdx.x*blockDim.x + threadIdx.x;
  if(i<n) p[i]=0;
}

// ---------------- CSR build ----------------
__global__ void k_hist(const int* __restrict__ dst, int* __restrict__ deg){
  int i = blockIdx.x*blockDim.x + threadIdx.x;
  if(i<EE) atomicAdd(&deg[dst[i]], 1);
}

__global__ void k_scan(const int* __restrict__ deg, int* __restrict__ rowptr){
  __shared__ int part[1024];
  int tid = threadIdx.x;
  const int n = NN;
  int chunk = (n + 1023)/1024;
  int start = tid*chunk;
  int end = start + chunk; if(end > n) end = n;
  int s = 0;
  for(int i=start;i<end;i++) s += deg[i];
  part[tid] = s; __syncthreads();
  for(int off=1; off<1024; off<<=1){
    int v = (tid>=off)? part[tid-off] : 0;
    __syncthreads();
    part[tid] += v;
    __syncthreads();
  }
  int run = (tid==0)? 0 : part[tid-1];
  for(int i=start;i<end;i++){ rowptr[i]=run; run += deg[i]; }
  if(tid==0) rowptr[n] = part[1023];
}

__global__ void k_scatter(const int* __restrict__ dst, const int* __restrict__ rowptr,
                          int* __restrict__ cursor, int* __restrict__ elist){
  int e = blockIdx.x*blockDim.x + threadIdx.x;
  if(e<EE){ int d=dst[e]; int p=atomicAdd(&cursor[d],1); elist[rowptr[d]+p]=e; }
}

// ------- time encoding: fp32 arg (mul then add, no FMA) to match f32 reference -------
__global__ void k_relenc(const int* __restrict__ src, const int* __restrict__ tt,
                         const int* __restrict__ lu, const float* __restrict__ tw,
                         const float* __restrict__ tb, bf16* __restrict__ rel){
  int i = blockIdx.x*blockDim.x + threadIdx.x;
  if(i >= EE*100) return;
  int e = i/100, c = i - e*100;
  float rt  = (float)(lu[src[e]] - tt[e]);
  float arg = __fadd_rn(__fmul_rn(rt, tw[c]), tb[c]);
  rel[i] = f2b(cosf(arg));
}

// ------- generic weight strip transpose: out row n = W col (colofs+n), bf16, zero-pad --
__global__ void k_wt2(const float* __restrict__ W, int K, int N, int colofs, int ncols,
                      bf16* __restrict__ WT, int kpad, int nrows){
  int i = blockIdx.x*blockDim.x + threadIdx.x;
  if(i >= nrows*kpad) return;
  int n = i / kpad, k = i - n*kpad;
  float v = (n<ncols && k<K)? W[(size_t)k*N + colofs + n] : 0.f;
  WT[i] = f2b(v);
}

// ------- conv1 stacked weights: 8 heads x [400 rows: q|k|v|s][128] from 4x [100,800] ---
__global__ void k_wtc1(const float* __restrict__ qw, const float* __restrict__ kw,
                       const float* __restrict__ vw, const float* __restrict__ sw,
                       bf16* __restrict__ outp){
  int i = blockIdx.x*blockDim.x + threadIdx.x;
  if(i >= 8*400*128) return;
  int h = i/(400*128), r = (i/128)%400, k = i&127;
  int s = r/100, n = r - s*100;
  const float* W = s==0? qw : s==1? kw : s==2? vw : sw;
  float v = (k<100)? W[(size_t)k*800 + h*100 + n] : 0.f;
  outp[i] = f2b(v);
}

// ------- conv1 edge weights: 8 heads x [112][256] from c1_ew [200,800] ----------------
__global__ void k_wtc1e(const float* __restrict__ ew, bf16* __restrict__ outp){
  int i = blockIdx.x*blockDim.x + threadIdx.x;
  if(i >= 8*112*256) return;
  int h = i/(112*256), r = (i/256)%112, k = i&255;
  float v = (r<100 && k<200)? ew[(size_t)k*800 + h*100 + r] : 0.f;
  outp[i] = f2b(v);
}

// ------- stacked bias: out[h][s][c] = b_s[h*W+c] ----------------
__global__ void k_bstack(const float* __restrict__ b0, const float* __restrict__ b1,
                         const float* __restrict__ b2, const float* __restrict__ b3,
                         int W, int H, float* __restrict__ outp){
  int i = blockIdx.x*blockDim.x + threadIdx.x;
  if(i >= H*4*W) return;
  int h = i/(4*W), r = i - h*4*W, s = r/W, c = r - s*W;
  const float* b = s==0? b0 : s==1? b1 : s==2? b2 : b3;
  outp[i] = b[h*W + c];
}

// ---------------- MFMA GEMM: C[M, NT*16] = A@W + bias ----------------
// A row: A1 bf16 for k<ksplit, else A2 fp32 (col k-ksplit). WT [NT*16][kpad] bf16 zero-pad.
// MFMA 16x16x32 layouts (m89-verified): A[m=lo][k=quad*8+j], B[k][n=lo], C col=lo,row=quad*4+r.
#define AK 128
#define AST 136   // 136 mod 64 == 8 -> ds_read_b128 2-way bank alias (free)

template<int NT>
__global__ __launch_bounds__(256) void mm_mfma(
    const bf16* __restrict__ A1, int lda1, int ksplit,
    const float* __restrict__ A2, int lda2,
    const bf16* __restrict__ WT, int kpad,
    const float* __restrict__ bias,
    bf16* __restrict__ C, int ldc,
    int M, int K, int nvalid, int act)
{
  __shared__ __align__(16) bf16 As[64*AST];
  int tid = threadIdx.x;
  int wave = tid>>6, lane = tid&63;
  int quad = lane>>4, lo = lane&15;
  int m0 = blockIdx.x*64;
  f32x4 acc[NT];
#pragma unroll
  for(int t=0;t<NT;t++) acc[t]=(f32x4){0.f,0.f,0.f,0.f};
  int nchunks = kpad/AK;
  for(int kc=0; kc<nchunks; kc++){
    int kbase = kc*AK;
    for(int idx=tid; idx<64*AK; idx+=256){
      int r = idx>>7, k = idx & 127;
      int row = m0 + r;
      int kk = kbase + k;
      float v = 0.f;
      if(row < M && kk < K){
        v = (kk < ksplit)? b2f(A1[(size_t)row*lda1+kk]) : A2[(size_t)row*lda2 + (kk-ksplit)];
      }
      As[r*AST + k] = f2b(v);
    }
    __syncthreads();
    const bf16* arow = As + (wave*16 + lo)*AST;
#pragma unroll
    for(int ks=0; ks<4; ks++){
      s16x8 af = *(const s16x8*)(arow + ks*32 + quad*8);
#pragma unroll
      for(int nt=0; nt<NT; nt++){
        const bf16* bp = WT + (size_t)(nt*16+lo)*kpad + kbase + ks*32 + quad*8;
        s16x8 bfr = *(const s16x8*)bp;
        acc[nt] = __builtin_amdgcn_mfma_f32_16x16x32_bf16(af, bfr, acc[nt], 0,0,0);
      }
    }
    __syncthreads();
  }
  int mrow0 = m0 + wave*16 + quad*4;
#pragma unroll
  for(int nt=0; nt<NT; nt++){
    int col = nt*16 + lo;
    if(col >= nvalid) continue;
    float bv = bias? bias[col] : 0.f;
#pragma unroll
    for(int r=0;r<4;r++){
      int row = mrow0 + r;
      if(row >= M) continue;
      float v = acc[nt][r] + bv;
      if(act) v = fmaxf(v,0.f);
      C[(size_t)row*ldc+col] = f2b(v);
    }
  }
}

// ------ fused attention: one wave per node; online softmax; skip-add + relu ------
// qkvs [N][400] = q|k|v|spre. eh [E][100]. hout row stride ldh, column offset colofs.
__global__ __launch_bounds__(256) void k_attn(
    const int* __restrict__ rowptr, const int* __restrict__ elist,
    const int* __restrict__ srcv,
    const bf16* __restrict__ qkvs, const bf16* __restrict__ eh,
    bf16* __restrict__ hout, int ldh, int colofs)
{
  int wave = threadIdx.x>>6, lane = threadIdx.x&63;
  int node = blockIdx.x*4 + wave;
  if(node >= NN) return;
  bool act = (lane < 50);
  float q0=0.f, q1=0.f;
  const unsigned* qrow = (const unsigned*)(qkvs + (size_t)node*400);
  if(act){ unsigned u = qrow[lane]; q0=u2f_lo(u); q1=u2f_hi(u); }
  int s0 = rowptr[node], s1 = rowptr[node+1];
  float m = -3.4e38f, d = 0.f, a0 = 0.f, a1 = 0.f;
  for(int j=s0; j<s1; j++){
    int e = elist[j];
    int sn = srcv[e];
    float p = 0.f, e0=0.f, e1=0.f;
    if(act){
      unsigned uk = ((const unsigned*)(qkvs + (size_t)sn*400 + 100))[lane];
      unsigned ue = ((const unsigned*)(eh   + (size_t)e*100))[lane];
      e0=u2f_lo(ue); e1=u2f_hi(ue);
      p = q0*(u2f_lo(uk)+e0) + q1*(u2f_hi(uk)+e1);
    }
    for(int off=32; off; off>>=1) p += __shfl_xor(p, off);
    float alpha = p * 0.1f;
    float mn = fmaxf(m, alpha);
    float sc = expf(m - mn);         // first edge: exp(-3.4e38-..)=0
    float wv = expf(alpha - mn);
    d = d*sc + wv;
    if(act){
      unsigned uv = ((const unsigned*)(qkvs + (size_t)sn*400 + 200))[lane];
      a0 = a0*sc + wv*(u2f_lo(uv)+e0);
      a1 = a1*sc + wv*(u2f_hi(uv)+e1);
    }
    m = mn;
  }
  if(act){
    float inv = 1.f/(d + 1e-16f);
    unsigned us = ((const unsigned*)(qkvs + (size_t)node*400 + 300))[lane];
    float h0 = fmaxf(u2f_lo(us) + a0*inv, 0.f);
    float h1 = fmaxf(u2f_hi(us) + a1*inv, 0.f);
    bf16* op = hout + (size_t)node*ldh + colofs + lane*2;
    op[0] = f2b(h0); op[1] = f2b(h1);
  }
}

// ---------------- fused MFMA link predictor: 16 edges/block, LDS 49 KB -------------
// all LDS row strides == 8 (mod 64) bf16 -> conflict-free ds_read_b128 (2-way only)
template<int KSTEPS>
static __device__ __forceinline__ void lp_gemm16(const bf16* Alds, int ast,
    const bf16* __restrict__ WT, int kpad,
    const float* __restrict__ bias, int ntiles, int nvalid,
    bf16* Olds, int ost, int act_tanh, int coloff, int wave, int quad, int lo)
{
  for(int nt=wave; nt<ntiles; nt+=4){
    f32x4 acc = (f32x4){0.f,0.f,0.f,0.f};
    const bf16* ar = Alds + lo*ast;
    const bf16* br = WT + (size_t)(nt*16+lo)*kpad;
#pragma unroll
    for(int ks=0; ks<KSTEPS; ks++){
      s16x8 af  = *(const s16x8*)(ar + ks*32 + quad*8);
      s16x8 bfr = *(const s16x8*)(br + ks*32 + quad*8);
      acc = __builtin_amdgcn_mfma_f32_16x16x32_bf16(af, bfr, acc, 0,0,0);
    }
    int col = nt*16+lo;
    if(col < nvalid){
      float bv = bias? bias[col] : 0.f;
#pragma unroll
      for(int r=0;r<4;r++){
        float v = acc[r] + bv;
        if(act_tanh) v = tanhf(v);
        Olds[(quad*4+r)*ost + coloff + col] = f2b(v);
      }
    }
  }
}

__global__ __launch_bounds__(256) void k_linkpred(
    const bf16* __restrict__ h2, const int* __restrict__ srcv, const int* __restrict__ dstv,
    const bf16* __restrict__ wst, const float* __restrict__ bsrc,
    const bf16* __restrict__ wdt, const float* __restrict__ bdst,
    const bf16* __restrict__ w1t, const float* __restrict__ pb1,
    const bf16* __restrict__ w2t, const float* __restrict__ pb2,
    const bf16* __restrict__ w3t, const float* __restrict__ pb3,
    const float* __restrict__ w4, const float* __restrict__ pb4,
    float* __restrict__ out)
{
  __shared__ __align__(16) bf16 sm_xs[16*136];   // 4.3 KB
  __shared__ __align__(16) bf16 sm_xd[16*136];   // 4.3 KB
  __shared__ __align__(16) bf16 sm_hh[16*456];   // 14.6 KB (hh; later t2 @ stride 264)
  __shared__ __align__(16) bf16 sm_t1[16*840];   // 26.9 KB
  int tid = threadIdx.x;
  int wave = tid>>6, lane = tid&63;
  int quad = lane>>4, lo = lane&15;
  int e0 = blockIdx.x*16;

  for(int idx=tid; idx<16*128; idx+=256){
    int g = idx>>7, k = idx&127;
    int e = e0 + g;
    float vs=0.f, vd=0.f;
    if(e<EE && k<100){
      vs = b2f(h2[(size_t)srcv[e]*100+k]);
      vd = b2f(h2[(size_t)dstv[e]*100+k]);
    }
    sm_xs[g*136+k] = f2b(vs);
    sm_xd[g*136+k] = f2b(vd);
  }
  for(int idx=tid; idx<16*16; idx+=256){    // zero hh cols 400..415 (KSTEPS=13 pad)
    int r = idx>>4, c = idx&15;
    sm_hh[r*456+400+c] = f2b(0.f);
  }
  __syncthreads();

  // layer1: hh[:,0:200]=xs@wsrc+bsrc; hh[:,200:400]=xd@wdst+bdst
  lp_gemm16<4>(sm_xs,136, wst,128, bsrc, 13,200, sm_hh,456, 0, 0,   wave,quad,lo);
  lp_gemm16<4>(sm_xd,136, wdt,128, bdst, 13,200, sm_hh,456, 0, 200, wave,quad,lo);
  __syncthreads();

  // layer2: t1 = tanh(hh @ w1 + b1)  K=400(13 steps), N=800
  lp_gemm16<13>(sm_hh,456, w1t,512, pb1, 50,800, sm_t1,840, 1, 0, wave,quad,lo);
  __syncthreads();

  // layer3: t2 = tanh(t1 @ w2 + b2)  K=800(25), N=200 -> overlay hh @ stride 264
  bf16* t2 = sm_hh;
  for(int idx=tid; idx<16*24; idx+=256){    // zero t2 cols 200..223 (KSTEPS=7 pad)
    int r = idx/24, c = idx - r*24;
    t2[r*264+200+c] = f2b(0.f);
  }
  lp_gemm16<25>(sm_t1,840, w2t,896, pb2, 13,200, t2,264, 1, 0, wave,quad,lo);
  __syncthreads();

  // layer4: t3 = tanh(t2 @ w3 + b3)  K=200(7), N=50 -> overlay xs @ stride 50
  bf16* t3 = sm_xs;
  lp_gemm16<7>(t2,264, w3t,256, pb3, 4,50, t3,50, 1, 0, wave,quad,lo);
  __syncthreads();

  if(tid < 32){
    int g = tid>>1, j = tid&1;
    int e = e0 + g;
    if(e < EE){
      float s = 0.f;
      for(int k=0;k<50;k++) s += b2f(t3[g*50+k])*w4[k*2+j];
      out[(size_t)e*2+j] = s + pb4[j];
    }
  }
}

extern "C" void kernel_launch(void* const* d_in, const int* in_sizes, int n_in,
                              void* d_out, int out_size, void* d_ws, size_t ws_size,
                              hipStream_t stream){
  const float* x       = (const float*)d_in[0];
  const float* msg     = (const float*)d_in[1];
  const float* time_w  = (const float*)d_in[2];
  const float* time_b  = (const float*)d_in[3];
  const float* c1_qw=(const float*)d_in[4];  const float* c1_qb=(const float*)d_in[5];
  const float* c1_kw=(const float*)d_in[6];  const float* c1_kb=(const float*)d_in[7];
  const float* c1_vw=(const float*)d_in[8];  const float* c1_vb=(const float*)d_in[9];
  const float* c1_ew=(const float*)d_in[10];
  const float* c1_sw=(const float*)d_in[11]; const float* c1_sb=(const float*)d_in[12];
  const float* c2_qw=(const float*)d_in[13]; const float* c2_qb=(const float*)d_in[14];
  const float* c2_kw=(const float*)d_in[15]; const float* c2_kb=(const float*)d_in[16];
  const float* c2_vw=(const float*)d_in[17]; const float* c2_vb=(const float*)d_in[18];
  const float* c2_ew=(const float*)d_in[19];
  const float* c2_sw=(const float*)d_in[20]; const float* c2_sb=(const float*)d_in[21];
  const float* lp_src_w=(const float*)d_in[22]; const float* lp_src_b=(const float*)d_in[23];
  const float* lp_dst_w=(const float*)d_in[24]; const float* lp_dst_b=(const float*)d_in[25];
  const float* lp1_w=(const float*)d_in[26]; const float* lp1_b=(const float*)d_in[27];
  const float* lp2_w=(const float*)d_in[28]; const float* lp2_b=(const float*)d_in[29];
  const float* lp3_w=(const float*)d_in[30]; const float* lp3_b=(const float*)d_in[31];
  const float* lp4_w=(const float*)d_in[32]; const float* lp4_b=(const float*)d_in[33];
  const int* last_update=(const int*)d_in[34];
  const int* tt =(const int*)d_in[35];
  const int* edge_index=(const int*)d_in[36];
  const int* src = edge_index;
  const int* dst = edge_index + EE;
  float* out = (float*)d_out;

  // ---- workspace: peak 194.6 MB (< proved-safe 201.8 MB) ----
  char* ws = (char*)d_ws;
  bf16*  h1    = (bf16*) (ws + 0);             // N*800 bf16
  bf16*  rel   = (bf16*) (ws + 80000000);      // E*100 bf16
  bf16*  eh    = (bf16*) (ws + 110000000);     // E*100 bf16 (per-head e)
  bf16*  qkvs  = (bf16*) (ws + 140000000);     // N*400 bf16 (q|k|v|spre)
  bf16*  h2    = (bf16*) (ws + 180000000);     // N*100 bf16
  int*   rowptr= (int*)  (ws + 190000000);     // N+1
  int*   elist = (int*)  (ws + 190200064);     // E
  int*   deg   = (int*)  (ws + 190800064);     // N
  int*   cursor= (int*)  (ws + 191000064);     // N
  bf16* c1all  = (bf16*)(ws + 191200064);  // 8 x [400][128]
  bf16* c1eall = (bf16*)(ws + 192019264);  // 8 x [112][256]
  bf16* c2all  = (bf16*)(ws + 192478016);  // [400][896]
  bf16* c2e    = (bf16*)(ws + 193194816);  // [112][256]
  bf16* lpswt  = (bf16*)(ws + 193252160);  // [208][128]
  bf16* lpdwt  = (bf16*)(ws + 193305408);  // [208][128]
  bf16* lp1t   = (bf16*)(ws + 193358656);  // [800][512]
  bf16* lp2t   = (bf16*)(ws + 194177856);  // [208][896]
  bf16* lp3t   = (bf16*)(ws + 194550592);  // [64][256]
  float* c1ball= (float*)(ws + 194583360); // [8][400]
  float* c2ball= (float*)(ws + 194596160); // [400] -> ends 194,597,760

  // ---- weight conversion ----
  k_wtc1 <<<(8*400*128+255)/256,256,0,stream>>>(c1_qw,c1_kw,c1_vw,c1_sw,c1all);
  k_wtc1e<<<(8*112*256+255)/256,256,0,stream>>>(c1_ew,c1eall);
  k_wt2<<<(100*896+255)/256,256,0,stream>>>(c2_qw,800,100,0,100,c2all,           896,100);
  k_wt2<<<(100*896+255)/256,256,0,stream>>>(c2_kw,800,100,0,100,c2all+100*896,   896,100);
  k_wt2<<<(100*896+255)/256,256,0,stream>>>(c2_vw,800,100,0,100,c2all+200*896,   896,100);
  k_wt2<<<(100*896+255)/256,256,0,stream>>>(c2_sw,800,100,0,100,c2all+300*896,   896,100);
  k_wt2<<<(112*256+255)/256,256,0,stream>>>(c2_ew,200,100,0,100,c2e,256,112);
  k_wt2<<<(208*128+255)/256,256,0,stream>>>(lp_src_w,100,200,0,200,lpswt,128,208);
  k_wt2<<<(208*128+255)/256,256,0,stream>>>(lp_dst_w,100,200,0,200,lpdwt,128,208);
  k_wt2<<<(800*512+255)/256,256,0,stream>>>(lp1_w,400,800,0,800,lp1t,512,800);
  k_wt2<<<(208*896+255)/256,256,0,stream>>>(lp2_w,800,200,0,200,lp2t,896,208);
  k_wt2<<<(64*256+255)/256,256,0,stream>>>(lp3_w,200,50,0,50,lp3t,256,64);
  k_bstack<<<(3200+255)/256,256,0,stream>>>(c1_qb,c1_kb,c1_vb,c1_sb,100,8,c1ball);
  k_bstack<<<(400+255)/256,256,0,stream>>>(c2_qb,c2_kb,c2_vb,c2_sb,100,1,c2ball);

  // ---- CSR build ----
  k_zero   <<<(NN+255)/256, 256, 0, stream>>>(deg, NN);
  k_zero   <<<(NN+255)/256, 256, 0, stream>>>(cursor, NN);
  k_hist   <<<(EE+255)/256, 256, 0, stream>>>(dst, deg);
  k_scan   <<<1, 1024, 0, stream>>>(deg, rowptr);
  k_scatter<<<(EE+255)/256, 256, 0, stream>>>(dst, rowptr, cursor, elist);

  // ---- time encoding ----
  k_relenc<<<(EE*100+255)/256, 256, 0, stream>>>(src, tt, last_update, time_w, time_b, rel);

  int gN = (NN+63)/64, gE = (EE+63)/64, gA = (NN+3)/4;

  // ---- conv1: per head = 1 stacked GEMM + 1 edge GEMM + 1 fused attention ----
  for(int h=0; h<8; h++){
    mm_mfma<25><<<gN,256,0,stream>>>(nullptr,0,0, x,100,
        c1all + (size_t)h*400*128, 128, c1ball + h*400, qkvs,400, NN,100,400,0);
    mm_mfma<7><<<gE,256,0,stream>>>(rel,100,100, msg,100,
        c1eall + (size_t)h*112*256, 256, nullptr, eh,100, EE,200,100,0);
    k_attn<<<gA,256,0,stream>>>(rowptr, elist, src, qkvs, eh, h1, 800, h*100);
  }

  // ---- conv2 ----
  mm_mfma<25><<<gN,256,0,stream>>>(h1,800,800, nullptr,0, c2all,896, c2ball, qkvs,400, NN,800,400,0);
  mm_mfma<7><<<gE,256,0,stream>>>(rel,100,100, msg,100, c2e,256, nullptr, eh,100, EE,200,100,0);
  k_attn<<<gA,256,0,stream>>>(rowptr, elist, src, qkvs, eh, h2, 100, 0);

  // ---- link predictor ----
  k_linkpred<<<(EE+15)/16, 256, 0, stream>>>(h2, src, dst,
      lpswt, lp_src_b, lpdwt, lp_dst_b,
      lp1t, lp1_b, lp2t, lp2_b, lp3t, lp3_b, lp4_w, lp4_b, out);

  (void)in_sizes; (void)n_in; (void)out_size; (void)ws_size;
}